// Round 11
// baseline (175.206 us; speedup 1.0000x reference)
//
#include <hip/hip_runtime.h>
#include <math.h>

#define B_  4
#define T_  16
#define C_  64
#define CQ_ 8
#define HW_ 9216          // 96*96
#define NCH_ 576          // HW_/16 energy chunks

typedef __attribute__((ext_vector_type(8))) short    s16x8;  // 8 bf16
typedef __attribute__((ext_vector_type(4))) float    f32x4;
typedef __attribute__((ext_vector_type(4))) unsigned u32x4;

static __device__ __forceinline__ short f2bf(float f) {
  union { float f; unsigned u; } v; v.f = f;
  return (short)((v.u + 0x7FFFu + ((v.u >> 16) & 1u)) >> 16);  // RNE
}
static __device__ __forceinline__ unsigned pkbf(float lo, float hi) {
  unsigned r;
  asm("v_cvt_pk_bf16_f32 %0, %1, %2" : "=v"(r) : "v"(lo), "v"(hi));
  return r;   // low16 = bf16(lo), high16 = bf16(hi)
}
static __device__ __forceinline__ float ubf(unsigned u) {
  union { unsigned u; float f; } v; v.u = u; return v.f;
}

// ---------------------------------------------------------------------------
// k_prep: (a) prepack conv weights as MFMA A-fragments (bf16);
//         (b) prepack Wv to bf16 in k_mix GEMM2 A-fragment order (wvb).
// ---------------------------------------------------------------------------
__global__ __launch_bounds__(256)
void k_prep(const float* __restrict__ wq, const float* __restrict__ wk,
            const float* __restrict__ wv, short* __restrict__ wqkb,
            short* __restrict__ wvb) {
  for (int idx = threadIdx.x; idx < 3072; idx += 256) {
    int j = idx & 7, lane = (idx >> 3) & 63, ks = idx >> 9;
    int m = lane & 15, lq = lane >> 4;
    int ci = (ks & 1) * 32 + lq * 8 + j;
    int d  = ks >> 1;
    float wval = (m < 8) ? wq[(m * C_ + ci) * 3 + d]
                         : wk[((m - 8) * C_ + ci) * 3 + d];
    wqkb[idx] = f2bf(wval);
  }
  for (int idx = threadIdx.x; idx < 4096; idx += 256) {
    int j = idx & 7, lane = (idx >> 3) & 63, fr = idx >> 9;  // fr = ct*2+ks
    int ct = fr >> 1, ks = fr & 1;
    int c  = ct * 16 + (lane & 15);
    int ci = ks * 32 + (lane >> 4) * 8 + j;
    wvb[idx] = f2bf(wv[c * C_ + ci]);
  }
}

// ---------------------------------------------------------------------------
// k_energy (all-MFMA, round 10 structure; partE stores now non-temporal).
// ---------------------------------------------------------------------------
__global__ __launch_bounds__(512, 4)
void k_energy(const float* __restrict__ x, const short* __restrict__ wqkb,
              const float* __restrict__ bq, const float* __restrict__ bk,
              float* __restrict__ partE) {
  __shared__ __attribute__((aligned(16))) short sh[29440];  // xs 20736 + qk 8704
  __shared__ float Ered[1024];

  const int b    = blockIdx.y;
  const int hw0  = blockIdx.x * 16;
  const int tid  = threadIdx.x;
  const int lane = tid & 63, w = tid >> 6;
  const int l15  = lane & 15, lq = lane >> 4;
  const f32x4 fz = {0.f, 0.f, 0.f, 0.f};

  // phase 0: zero pad rows (s = -1 and s = 16)
  for (int i = tid; i < 1152; i += 512)
    ((unsigned*)sh)[(i < 576) ? i : (9216 + i)] = 0;

  // A-frags (conv weights), coalesced 16B/lane
  s16x8 afr[6];
#pragma unroll
  for (int ks = 0; ks < 6; ++ks)
    afr[ks] = *(const s16x8*)&wqkb[(ks * 64 + lane) * 8];

  // bias for my 4 output rows m = lq*4+r  (m<8 -> q/bq, else k/bk)
  const float* bias = (lq < 2) ? bq : bk;
  const int cqb = (lq & 1) * 4;
  const float b0 = bias[cqb + 0], b1 = bias[cqb + 1];
  const float b2 = bias[cqb + 2], b3 = bias[cqb + 3];

  // phase 1: stage. thread = (s0, cp, q4); 8 float4 loads, 16 b32 writes.
  {
    const int q4 = tid & 3;          // g quad
    const int cp = (tid >> 2) & 31;  // ci pair (ci = 2cp, 2cp+1)
    const int s0 = tid >> 7;         // 0..3
    const float* xb = x + (size_t)(b * T_ * C_ + 2 * cp) * HW_ + hw0 + 4 * q4;
#pragma unroll
    for (int it = 0; it < 4; ++it) {
      const int s = s0 * 4 + it;
      float4 v0 = *(const float4*)(xb + (size_t)(s * C_) * HW_);
      float4 v1 = *(const float4*)(xb + (size_t)(s * C_) * HW_ + HW_);
      const int off = ((cp >> 2) ^ ((s + 1) & 7)) * 8 + 2 * (cp & 3);
      const int rb  = (s + 1) * 16 + 4 * q4;
      *(unsigned*)&sh[(rb + 0) * 72 + off] = pkbf(v0.x, v1.x);
      *(unsigned*)&sh[(rb + 1) * 72 + off] = pkbf(v0.y, v1.y);
      *(unsigned*)&sh[(rb + 2) * 72 + off] = pkbf(v0.z, v1.z);
      *(unsigned*)&sh[(rb + 3) * 72 + off] = pkbf(v0.w, v1.w);
    }
  }
  __syncthreads();

  // phase 2: conv GEMM, wave w -> g = 2w, 2w+1
#pragma unroll
  for (int gl = 0; gl < 2; ++gl) {
    const int g = w * 2 + gl;
    f32x4 a = fz;
#pragma unroll
    for (int ks = 0; ks < 6; ++ks) {
      const int d = ks >> 1;
      const int row = (l15 + d) * 16 + g;           // s+1 = t+d
      const int chunk = (((ks & 1) * 4 + lq) ^ ((l15 + d) & 7));
      s16x8 bf = *(const s16x8*)&sh[row * 72 + chunk * 8];
      a = __builtin_amdgcn_mfma_f32_16x16x32_bf16(afr[ks], bf, a, 0, 0, 0);
    }
    const float v0 = a[0] + b0, v1 = a[1] + b1;
    const float v2 = a[2] + b2, v3 = a[3] + b3;
    const unsigned h01 = pkbf(v0, v1), h23 = pkbf(v2, v3);
    const unsigned l01 = pkbf(v0 - ubf(h01 << 16), v1 - ubf(h01 & 0xffff0000u));
    const unsigned l23 = pkbf(v2 - ubf(h23 << 16), v3 - ubf(h23 & 0xffff0000u));
    short* pl = &sh[20736 + (lq >> 1) * 4352 + l15 * 136 + g * 8 + (lq & 1) * 4];
    uint2 hh; hh.x = h01; hh.y = h23;
    uint2 ll; ll.x = l01; ll.y = l23;
    *(uint2*)pl          = hh;
    *(uint2*)(pl + 2176) = ll;
  }
  __syncthreads();

  // phase 3: E-dot, waves 0..3 take k-step eks = w (K = 128 over (g,cq))
  if (w < 4) {
    const int off = l15 * 136 + w * 32 + lq * 8;
    const short* Qp = &sh[20736];
    const short* Kp = &sh[20736 + 4352];
    s16x8 qh = *(const s16x8*)&Qp[off];
    s16x8 ql = *(const s16x8*)&Qp[off + 2176];
    s16x8 kh = *(const s16x8*)&Kp[off];
    s16x8 kl = *(const s16x8*)&Kp[off + 2176];
    f32x4 e = fz;
    e = __builtin_amdgcn_mfma_f32_16x16x32_bf16(qh, kh, e, 0, 0, 0);
    e = __builtin_amdgcn_mfma_f32_16x16x32_bf16(qh, kl, e, 0, 0, 0);
    e = __builtin_amdgcn_mfma_f32_16x16x32_bf16(ql, kh, e, 0, 0, 0);
#pragma unroll
    for (int r = 0; r < 4; ++r)
      Ered[w * 256 + (lq * 4 + r) * 16 + l15] = e[r];
  }
  __syncthreads();

  if (tid < 256) {
    float e = Ered[tid] + Ered[256 + tid] + Ered[512 + tid] + Ered[768 + tid];
    __builtin_nontemporal_store(
        e, &partE[((size_t)(b * NCH_ + blockIdx.x)) * 256 + tid]);
  }
}

// ---------------------------------------------------------------------------
// k_softmax: reduce 576 partials and softmax over s. grid 4, block 256.
// ---------------------------------------------------------------------------
__global__ __launch_bounds__(256)
void k_softmax(const float* __restrict__ partE, float* __restrict__ heat) {
  const int b = blockIdx.x;
  const int tid = threadIdx.x;
  float e = 0.f;
  for (int ch = 0; ch < NCH_; ++ch)
    e += __builtin_nontemporal_load(
        &partE[((size_t)(b * NCH_ + ch)) * 256 + tid]);
  float mx = e;
#pragma unroll
  for (int m = 1; m < 16; m <<= 1) mx = fmaxf(mx, __shfl_xor(mx, m, 64));
  float ex = expf(e - mx);
  float sm = ex;
#pragma unroll
  for (int m = 1; m < 16; m <<= 1) sm += __shfl_xor(sm, m, 64);
  heat[b * 256 + tid] = ex / sm;
}

// ---------------------------------------------------------------------------
// k_mix (MFMA): round-8 structure. Round-11: non-temporal out stores (out is
// write-once -> keep it OUT of L2/L3 so x stays L3-resident across kernels);
// __launch_bounds__(256,4) -> 4 blocks/CU (LDS 4x40KB = 160KB exactly).
// ---------------------------------------------------------------------------
__global__ __launch_bounds__(256, 4)
void k_mix(const float* __restrict__ x, const float* __restrict__ heat,
           const short* __restrict__ wvb, const float* __restrict__ bv,
           const float* __restrict__ gam, float* __restrict__ out) {
  __shared__ __attribute__((aligned(16))) short sm[20480];  // 40 KB union

  const int b    = blockIdx.y;
  const int hw0  = blockIdx.x * 16;
  const int tid  = threadIdx.x;
  const int lane = tid & 63;
  const int w    = tid >> 6;      // wave 0..3
  const int l15  = lane & 15;
  const int lq   = lane >> 4;     // quarter 0..3

  union U8 { s16x8 v; int i[4]; unsigned u[4]; };
  const f32x4 fz = {0.f, 0.f, 0.f, 0.f};

  // ---- A1 fragment first (needed by GEMM1; hides under staging loads) ----
  U8 ha; ha.i[0] = ha.i[1] = ha.i[2] = ha.i[3] = 0;
  if (lane < 32) {
    const float* hp = heat + b * 256 + l15 * 16 + lq * 8;
    float4 h0 = *(const float4*)hp;
    float4 h1 = *(const float4*)(hp + 4);
    ha.u[0] = pkbf(h0.x, h0.y); ha.u[1] = pkbf(h0.z, h0.w);
    ha.u[2] = pkbf(h1.x, h1.y); ha.u[3] = pkbf(h1.z, h1.w);
  }

  // ---- stage x tile -> bf16 xs: row (ci*16+g), stride 20 shorts,
  //      s-pairs packed as ints at int-index (P ^ (ci&7)) ------------------
  {
    const int ci = tid >> 2, q = tid & 3;
    const int sx = ci & 7;
    const float* xp = x + ((size_t)b * T_ * C_ + ci) * HW_ + hw0 + q * 4;
    short* r0 = &sm[(ci * 16 + q * 4) * 20];
#pragma unroll
    for (int P = 0; P < 8; ++P) {
      float4 v0 = *(const float4*)(xp + (size_t)(2 * P) * C_ * HW_);
      float4 v1 = *(const float4*)(xp + (size_t)(2 * P + 1) * C_ * HW_);
      const int ip = (P ^ sx) * 2;    // short offset, 4B-aligned
      *(unsigned*)&r0[ip]      = pkbf(v0.x, v1.x);
      *(unsigned*)&r0[20 + ip] = pkbf(v0.y, v1.y);
      *(unsigned*)&r0[40 + ip] = pkbf(v0.z, v1.z);
      *(unsigned*)&r0[60 + ip] = pkbf(v0.w, v1.w);
    }
  }

  // ---- a2 fragments (prepacked bf16), issued now, consumed after GEMM1 ---
  U8 a2[8];
#pragma unroll
  for (int fr = 0; fr < 8; ++fr)
    a2[fr].v = *(const s16x8*)&wvb[(fr * 64 + lane) * 8];

  // wave-local: my staging writes are the only rows my GEMM1 reads
  asm volatile("s_waitcnt lgkmcnt(0)" ::: "memory");

  // ---- GEMM1: 16 MFMAs, ci = w*16+i (own staged rows, no barrier) --------
  const int lq2 = lq & 1;   // lanes lq>=2 alias lq-2's B rows (A there is 0)
  f32x4 c1[16];
#pragma unroll
  for (int i = 0; i < 16; ++i) {
    const int ci = w * 16 + i;
    const short* row = &sm[(ci * 16 + l15) * 20];
    const int base = (lq2 * 4) ^ (i & 4);          // int index, even
    int2 D0 = *(const int2*)&row[2 * base];        // ints base, base+1
    int2 D1 = *(const int2*)&row[2 * base + 4];    // ints base+2, base+3
    U8 bx;
    const int t3 = i & 3;                          // compile-time per iter
    bx.i[0] = (t3 == 0) ? D0.x : (t3 == 1) ? D0.y : (t3 == 2) ? D1.x : D1.y;
    bx.i[1] = (t3 == 0) ? D0.y : (t3 == 1) ? D0.x : (t3 == 2) ? D1.y : D1.x;
    bx.i[2] = (t3 == 0) ? D1.x : (t3 == 1) ? D1.y : (t3 == 2) ? D0.x : D0.y;
    bx.i[3] = (t3 == 0) ? D1.y : (t3 == 1) ? D1.x : (t3 == 2) ? D0.y : D0.x;
    c1[i] = __builtin_amdgcn_mfma_f32_16x16x32_bf16(ha.v, bx.v, fz, 0, 0, 0);
  }
  __syncthreads();   // all staging complete -> rc may read any row

  // ---- residual from LDS (xs): rc[(ct*4+r)*2+h] = int holding bf16 pair
  unsigned rc[32];
#pragma unroll
  for (int ct = 0; ct < 4; ++ct)
#pragma unroll
    for (int r = 0; r < 4; ++r) {
      const int c = ct * 16 + lq * 4 + r;
      const short* row = &sm[(c * 16 + l15) * 20];
      const int base = 4 * ((w >> 1) ^ (lq & 1)) + 2 * ((w & 1) ^ (r >> 1));
      int2 D = *(const int2*)&row[2 * base];
      rc[(ct * 4 + r) * 2 + 0] = (r & 1) ? (unsigned)D.y : (unsigned)D.x;
      rc[(ct * 4 + r) * 2 + 1] = (r & 1) ? (unsigned)D.x : (unsigned)D.y;
    }
  __syncthreads();   // all xs reads done; sm becomes xh

  // ---- write xh -> LDS [n=t*16+g][ci] (stride 72), ci-pairs cvt_pk'd -----
#pragma unroll
  for (int r = 0; r < 4; ++r) {
    const int t = lq * 4 + r;
    short* dst = &sm[(t * 16 + l15) * 72 + w * 16];
    u32x4 p0, p1;
    p0[0] = pkbf(c1[0][r],  c1[1][r]);  p0[1] = pkbf(c1[2][r],  c1[3][r]);
    p0[2] = pkbf(c1[4][r],  c1[5][r]);  p0[3] = pkbf(c1[6][r],  c1[7][r]);
    p1[0] = pkbf(c1[8][r],  c1[9][r]);  p1[1] = pkbf(c1[10][r], c1[11][r]);
    p1[2] = pkbf(c1[12][r], c1[13][r]); p1[3] = pkbf(c1[14][r], c1[15][r]);
    *(u32x4*)dst       = p0;
    *(u32x4*)(dst + 8) = p1;
  }

  f32x4 bvr[4];
#pragma unroll
  for (int ct = 0; ct < 4; ++ct)
    bvr[ct] = *(const f32x4*)(bv + ct * 16 + lq * 4);
  const float gamma = gam[0];
  __syncthreads();   // xh visible

  // ---- GEMM2 + epilogue (non-temporal stores): wave owns t = w*4..w*4+3 --
#pragma unroll
  for (int ntq = 0; ntq < 4; ++ntq) {
    const int t = w * 4 + ntq;
    const short* xr0 = &sm[(t * 16 + l15) * 72];
    s16x8 b0 = *(const s16x8*)(xr0 + lq * 8);        // k = ci   0..31 slice
    s16x8 b1 = *(const s16x8*)(xr0 + 32 + lq * 8);   // k = ci  32..63 slice
    float* op = out + ((size_t)(b * T_ + t) * C_) * HW_ + hw0 + l15;
    const int half = ntq >> 1, odd = ntq & 1;
#pragma unroll
    for (int ct = 0; ct < 4; ++ct) {
      f32x4 acc = __builtin_amdgcn_mfma_f32_16x16x32_bf16(a2[ct * 2 + 0].v, b0, fz, 0, 0, 0);
      acc = __builtin_amdgcn_mfma_f32_16x16x32_bf16(a2[ct * 2 + 1].v, b1, acc, 0, 0, 0);
      const int cb = ct * 16 + lq * 4;
#pragma unroll
      for (int r = 0; r < 4; ++r) {
        const unsigned v = rc[(ct * 4 + r) * 2 + half];
        union { unsigned u; float f; } z;
        z.u = odd ? (v & 0xffff0000u) : (v << 16);
        __builtin_nontemporal_store(
            gamma * (acc[r] + bvr[ct][r]) + z.f,
            &op[(size_t)(cb + r) * HW_]);
      }
    }
  }
}

// ---------------------------------------------------------------------------
extern "C" void kernel_launch(void* const* d_in, const int* in_sizes, int n_in,
                              void* d_out, int out_size, void* d_ws, size_t ws_size,
                              hipStream_t stream) {
  const float* x   = (const float*)d_in[0];
  const float* wq  = (const float*)d_in[1];
  const float* bq  = (const float*)d_in[2];
  const float* wk  = (const float*)d_in[3];
  const float* bk  = (const float*)d_in[4];
  const float* wv  = (const float*)d_in[5];
  const float* bv  = (const float*)d_in[6];
  const float* gam = (const float*)d_in[7];
  float* out = (float*)d_out;

  short* wqkb  = (short*)d_ws;                        // 3072 bf16
  short* wvb   = wqkb + 3072;                         // 4096 bf16
  float* partE = (float*)(wvb + 4096 + 1024);         // pad to 16B; 4*576*256 f
  float* heat  = partE + (size_t)B_ * NCH_ * 256;     // 4*256 floats

  k_prep   <<<1, 256, 0, stream>>>(wq, wk, wv, wqkb, wvb);
  k_energy <<<dim3(NCH_, B_), 512, 0, stream>>>(x, wqkb, bq, bk, partE);
  k_softmax<<<dim3(B_),       256, 0, stream>>>(partE, heat);
  k_mix    <<<dim3(HW_ / 16, B_), 256, 0, stream>>>(x, heat, wvb, bv, gam, out);
}

// Round 12
// 147.976 us; speedup vs baseline: 1.1840x; 1.1840x over previous
//
#include <hip/hip_runtime.h>
#include <math.h>

#define B_  4
#define T_  16
#define C_  64
#define CQ_ 8
#define HW_ 9216          // 96*96
#define NCH_ 576          // HW_/16 energy chunks

typedef __attribute__((ext_vector_type(8))) short    s16x8;  // 8 bf16
typedef __attribute__((ext_vector_type(4))) float    f32x4;
typedef __attribute__((ext_vector_type(4))) unsigned u32x4;

static __device__ __forceinline__ short f2bf(float f) {
  union { float f; unsigned u; } v; v.f = f;
  return (short)((v.u + 0x7FFFu + ((v.u >> 16) & 1u)) >> 16);  // RNE
}
static __device__ __forceinline__ unsigned pkbf(float lo, float hi) {
  unsigned r;
  asm("v_cvt_pk_bf16_f32 %0, %1, %2" : "=v"(r) : "v"(lo), "v"(hi));
  return r;   // low16 = bf16(lo), high16 = bf16(hi)
}
static __device__ __forceinline__ float ubf(unsigned u) {
  union { unsigned u; float f; } v; v.u = u; return v.f;
}

// ---------------------------------------------------------------------------
// k_prep: (a) prepack conv weights as MFMA A-fragments (bf16);
//         (b) prepack Wv to bf16 in k_mix GEMM2 A-fragment order (wvb).
// ---------------------------------------------------------------------------
__global__ __launch_bounds__(256)
void k_prep(const float* __restrict__ wq, const float* __restrict__ wk,
            const float* __restrict__ wv, short* __restrict__ wqkb,
            short* __restrict__ wvb) {
  for (int idx = threadIdx.x; idx < 3072; idx += 256) {
    int j = idx & 7, lane = (idx >> 3) & 63, ks = idx >> 9;
    int m = lane & 15, lq = lane >> 4;
    int ci = (ks & 1) * 32 + lq * 8 + j;
    int d  = ks >> 1;
    float wval = (m < 8) ? wq[(m * C_ + ci) * 3 + d]
                         : wk[((m - 8) * C_ + ci) * 3 + d];
    wqkb[idx] = f2bf(wval);
  }
  for (int idx = threadIdx.x; idx < 4096; idx += 256) {
    int j = idx & 7, lane = (idx >> 3) & 63, fr = idx >> 9;  // fr = ct*2+ks
    int ct = fr >> 1, ks = fr & 1;
    int c  = ct * 16 + (lane & 15);
    int ci = ks * 32 + (lane >> 4) * 8 + j;
    wvb[idx] = f2bf(wv[c * C_ + ci]);
  }
}

// ---------------------------------------------------------------------------
// k_energy (all-MFMA, round-10 structure, normal stores).
// ---------------------------------------------------------------------------
__global__ __launch_bounds__(512, 4)
void k_energy(const float* __restrict__ x, const short* __restrict__ wqkb,
              const float* __restrict__ bq, const float* __restrict__ bk,
              float* __restrict__ partE) {
  __shared__ __attribute__((aligned(16))) short sh[29440];  // xs 20736 + qk 8704
  __shared__ float Ered[1024];

  const int b    = blockIdx.y;
  const int hw0  = blockIdx.x * 16;
  const int tid  = threadIdx.x;
  const int lane = tid & 63, w = tid >> 6;
  const int l15  = lane & 15, lq = lane >> 4;
  const f32x4 fz = {0.f, 0.f, 0.f, 0.f};

  // phase 0: zero pad rows (s = -1 and s = 16)
  for (int i = tid; i < 1152; i += 512)
    ((unsigned*)sh)[(i < 576) ? i : (9216 + i)] = 0;

  // A-frags (conv weights), coalesced 16B/lane
  s16x8 afr[6];
#pragma unroll
  for (int ks = 0; ks < 6; ++ks)
    afr[ks] = *(const s16x8*)&wqkb[(ks * 64 + lane) * 8];

  // bias for my 4 output rows m = lq*4+r  (m<8 -> q/bq, else k/bk)
  const float* bias = (lq < 2) ? bq : bk;
  const int cqb = (lq & 1) * 4;
  const float b0 = bias[cqb + 0], b1 = bias[cqb + 1];
  const float b2 = bias[cqb + 2], b3 = bias[cqb + 3];

  // phase 1: stage. thread = (s0, cp, q4); 8 float4 loads, 16 b32 writes.
  {
    const int q4 = tid & 3;          // g quad
    const int cp = (tid >> 2) & 31;  // ci pair (ci = 2cp, 2cp+1)
    const int s0 = tid >> 7;         // 0..3
    const float* xb = x + (size_t)(b * T_ * C_ + 2 * cp) * HW_ + hw0 + 4 * q4;
#pragma unroll
    for (int it = 0; it < 4; ++it) {
      const int s = s0 * 4 + it;
      float4 v0 = *(const float4*)(xb + (size_t)(s * C_) * HW_);
      float4 v1 = *(const float4*)(xb + (size_t)(s * C_) * HW_ + HW_);
      const int off = ((cp >> 2) ^ ((s + 1) & 7)) * 8 + 2 * (cp & 3);
      const int rb  = (s + 1) * 16 + 4 * q4;
      *(unsigned*)&sh[(rb + 0) * 72 + off] = pkbf(v0.x, v1.x);
      *(unsigned*)&sh[(rb + 1) * 72 + off] = pkbf(v0.y, v1.y);
      *(unsigned*)&sh[(rb + 2) * 72 + off] = pkbf(v0.z, v1.z);
      *(unsigned*)&sh[(rb + 3) * 72 + off] = pkbf(v0.w, v1.w);
    }
  }
  __syncthreads();

  // phase 2: conv GEMM, wave w -> g = 2w, 2w+1
#pragma unroll
  for (int gl = 0; gl < 2; ++gl) {
    const int g = w * 2 + gl;
    f32x4 a = fz;
#pragma unroll
    for (int ks = 0; ks < 6; ++ks) {
      const int d = ks >> 1;
      const int row = (l15 + d) * 16 + g;           // s+1 = t+d
      const int chunk = (((ks & 1) * 4 + lq) ^ ((l15 + d) & 7));
      s16x8 bf = *(const s16x8*)&sh[row * 72 + chunk * 8];
      a = __builtin_amdgcn_mfma_f32_16x16x32_bf16(afr[ks], bf, a, 0, 0, 0);
    }
    const float v0 = a[0] + b0, v1 = a[1] + b1;
    const float v2 = a[2] + b2, v3 = a[3] + b3;
    const unsigned h01 = pkbf(v0, v1), h23 = pkbf(v2, v3);
    const unsigned l01 = pkbf(v0 - ubf(h01 << 16), v1 - ubf(h01 & 0xffff0000u));
    const unsigned l23 = pkbf(v2 - ubf(h23 << 16), v3 - ubf(h23 & 0xffff0000u));
    short* pl = &sh[20736 + (lq >> 1) * 4352 + l15 * 136 + g * 8 + (lq & 1) * 4];
    uint2 hh; hh.x = h01; hh.y = h23;
    uint2 ll; ll.x = l01; ll.y = l23;
    *(uint2*)pl          = hh;
    *(uint2*)(pl + 2176) = ll;
  }
  __syncthreads();

  // phase 3: E-dot, waves 0..3 take k-step eks = w (K = 128 over (g,cq))
  if (w < 4) {
    const int off = l15 * 136 + w * 32 + lq * 8;
    const short* Qp = &sh[20736];
    const short* Kp = &sh[20736 + 4352];
    s16x8 qh = *(const s16x8*)&Qp[off];
    s16x8 ql = *(const s16x8*)&Qp[off + 2176];
    s16x8 kh = *(const s16x8*)&Kp[off];
    s16x8 kl = *(const s16x8*)&Kp[off + 2176];
    f32x4 e = fz;
    e = __builtin_amdgcn_mfma_f32_16x16x32_bf16(qh, kh, e, 0, 0, 0);
    e = __builtin_amdgcn_mfma_f32_16x16x32_bf16(qh, kl, e, 0, 0, 0);
    e = __builtin_amdgcn_mfma_f32_16x16x32_bf16(ql, kh, e, 0, 0, 0);
#pragma unroll
    for (int r = 0; r < 4; ++r)
      Ered[w * 256 + (lq * 4 + r) * 16 + l15] = e[r];
  }
  __syncthreads();

  if (tid < 256) {
    float e = Ered[tid] + Ered[256 + tid] + Ered[512 + tid] + Ered[768 + tid];
    partE[((size_t)(b * NCH_ + blockIdx.x)) * 256 + tid] = e;
  }
}

// ---------------------------------------------------------------------------
// k_softmax: reduce 576 partials and softmax over s. grid 4, block 256.
// ---------------------------------------------------------------------------
__global__ __launch_bounds__(256)
void k_softmax(const float* __restrict__ partE, float* __restrict__ heat) {
  const int b = blockIdx.x;
  const int tid = threadIdx.x;
  float e = 0.f;
  for (int ch = 0; ch < NCH_; ++ch)
    e += partE[((size_t)(b * NCH_ + ch)) * 256 + tid];
  float mx = e;
#pragma unroll
  for (int m = 1; m < 16; m <<= 1) mx = fmaxf(mx, __shfl_xor(mx, m, 64));
  float ex = expf(e - mx);
  float sm = ex;
#pragma unroll
  for (int m = 1; m < 16; m <<= 1) sm += __shfl_xor(sm, m, 64);
  heat[b * 256 + tid] = ex / sm;
}

// ---------------------------------------------------------------------------
// k_mix (MFMA): exact round-10 structure (launch_bounds (256,3), VGPR 80,
// no spill). ONE change: `out` stores are non-temporal — out is write-once,
// never re-read; keeping it out of L2/L3 lets x (151 MB < 256 MB L3) stay
// L3-resident across k_energy and k_mix.
// ---------------------------------------------------------------------------
__global__ __launch_bounds__(256, 3)
void k_mix(const float* __restrict__ x, const float* __restrict__ heat,
           const short* __restrict__ wvb, const float* __restrict__ bv,
           const float* __restrict__ gam, float* __restrict__ out) {
  __shared__ __attribute__((aligned(16))) short sm[20480];  // 40 KB union

  const int b    = blockIdx.y;
  const int hw0  = blockIdx.x * 16;
  const int tid  = threadIdx.x;
  const int lane = tid & 63;
  const int w    = tid >> 6;      // wave 0..3
  const int l15  = lane & 15;
  const int lq   = lane >> 4;     // quarter 0..3

  union U8 { s16x8 v; int i[4]; unsigned u[4]; };
  const f32x4 fz = {0.f, 0.f, 0.f, 0.f};

  // ---- A1 fragment first (needed by GEMM1; hides under staging loads) ----
  U8 ha; ha.i[0] = ha.i[1] = ha.i[2] = ha.i[3] = 0;
  if (lane < 32) {
    const float* hp = heat + b * 256 + l15 * 16 + lq * 8;
    float4 h0 = *(const float4*)hp;
    float4 h1 = *(const float4*)(hp + 4);
    ha.u[0] = pkbf(h0.x, h0.y); ha.u[1] = pkbf(h0.z, h0.w);
    ha.u[2] = pkbf(h1.x, h1.y); ha.u[3] = pkbf(h1.z, h1.w);
  }

  // ---- stage x tile -> bf16 xs: row (ci*16+g), stride 20 shorts,
  //      s-pairs packed as ints at int-index (P ^ (ci&7)) ------------------
  {
    const int ci = tid >> 2, q = tid & 3;
    const int sx = ci & 7;
    const float* xp = x + ((size_t)b * T_ * C_ + ci) * HW_ + hw0 + q * 4;
    short* r0 = &sm[(ci * 16 + q * 4) * 20];
#pragma unroll
    for (int P = 0; P < 8; ++P) {
      float4 v0 = *(const float4*)(xp + (size_t)(2 * P) * C_ * HW_);
      float4 v1 = *(const float4*)(xp + (size_t)(2 * P + 1) * C_ * HW_);
      const int ip = (P ^ sx) * 2;    // short offset, 4B-aligned
      *(unsigned*)&r0[ip]      = pkbf(v0.x, v1.x);
      *(unsigned*)&r0[20 + ip] = pkbf(v0.y, v1.y);
      *(unsigned*)&r0[40 + ip] = pkbf(v0.z, v1.z);
      *(unsigned*)&r0[60 + ip] = pkbf(v0.w, v1.w);
    }
  }

  // ---- a2 fragments (prepacked bf16), issued now, consumed after GEMM1 ---
  U8 a2[8];
#pragma unroll
  for (int fr = 0; fr < 8; ++fr)
    a2[fr].v = *(const s16x8*)&wvb[(fr * 64 + lane) * 8];

  // wave-local: my staging writes are the only rows my GEMM1 reads
  asm volatile("s_waitcnt lgkmcnt(0)" ::: "memory");

  // ---- GEMM1: 16 MFMAs, ci = w*16+i (own staged rows, no barrier) --------
  const int lq2 = lq & 1;   // lanes lq>=2 alias lq-2's B rows (A there is 0)
  f32x4 c1[16];
#pragma unroll
  for (int i = 0; i < 16; ++i) {
    const int ci = w * 16 + i;
    const short* row = &sm[(ci * 16 + l15) * 20];
    const int base = (lq2 * 4) ^ (i & 4);          // int index, even
    int2 D0 = *(const int2*)&row[2 * base];        // ints base, base+1
    int2 D1 = *(const int2*)&row[2 * base + 4];    // ints base+2, base+3
    U8 bx;
    const int t3 = i & 3;                          // compile-time per iter
    bx.i[0] = (t3 == 0) ? D0.x : (t3 == 1) ? D0.y : (t3 == 2) ? D1.x : D1.y;
    bx.i[1] = (t3 == 0) ? D0.y : (t3 == 1) ? D0.x : (t3 == 2) ? D1.y : D1.x;
    bx.i[2] = (t3 == 0) ? D1.x : (t3 == 1) ? D1.y : (t3 == 2) ? D0.x : D0.y;
    bx.i[3] = (t3 == 0) ? D1.y : (t3 == 1) ? D1.x : (t3 == 2) ? D0.y : D0.x;
    c1[i] = __builtin_amdgcn_mfma_f32_16x16x32_bf16(ha.v, bx.v, fz, 0, 0, 0);
  }
  __syncthreads();   // all staging complete -> rc may read any row

  // ---- residual from LDS (xs): rc[(ct*4+r)*2+h] = int holding bf16 pair
  unsigned rc[32];
#pragma unroll
  for (int ct = 0; ct < 4; ++ct)
#pragma unroll
    for (int r = 0; r < 4; ++r) {
      const int c = ct * 16 + lq * 4 + r;
      const short* row = &sm[(c * 16 + l15) * 20];
      const int base = 4 * ((w >> 1) ^ (lq & 1)) + 2 * ((w & 1) ^ (r >> 1));
      int2 D = *(const int2*)&row[2 * base];
      rc[(ct * 4 + r) * 2 + 0] = (r & 1) ? (unsigned)D.y : (unsigned)D.x;
      rc[(ct * 4 + r) * 2 + 1] = (r & 1) ? (unsigned)D.x : (unsigned)D.y;
    }
  __syncthreads();   // all xs reads done; sm becomes xh

  // ---- write xh -> LDS [n=t*16+g][ci] (stride 72), ci-pairs cvt_pk'd -----
#pragma unroll
  for (int r = 0; r < 4; ++r) {
    const int t = lq * 4 + r;
    short* dst = &sm[(t * 16 + l15) * 72 + w * 16];
    u32x4 p0, p1;
    p0[0] = pkbf(c1[0][r],  c1[1][r]);  p0[1] = pkbf(c1[2][r],  c1[3][r]);
    p0[2] = pkbf(c1[4][r],  c1[5][r]);  p0[3] = pkbf(c1[6][r],  c1[7][r]);
    p1[0] = pkbf(c1[8][r],  c1[9][r]);  p1[1] = pkbf(c1[10][r], c1[11][r]);
    p1[2] = pkbf(c1[12][r], c1[13][r]); p1[3] = pkbf(c1[14][r], c1[15][r]);
    *(u32x4*)dst       = p0;
    *(u32x4*)(dst + 8) = p1;
  }

  f32x4 bvr[4];
#pragma unroll
  for (int ct = 0; ct < 4; ++ct)
    bvr[ct] = *(const f32x4*)(bv + ct * 16 + lq * 4);
  const float gamma = gam[0];
  __syncthreads();   // xh visible

  // ---- GEMM2 + epilogue (NT out stores): wave owns t = w*4..w*4+3 --------
#pragma unroll
  for (int ntq = 0; ntq < 4; ++ntq) {
    const int t = w * 4 + ntq;
    const short* xr0 = &sm[(t * 16 + l15) * 72];
    s16x8 b0 = *(const s16x8*)(xr0 + lq * 8);        // k = ci   0..31 slice
    s16x8 b1 = *(const s16x8*)(xr0 + 32 + lq * 8);   // k = ci  32..63 slice
    float* op = out + ((size_t)(b * T_ + t) * C_) * HW_ + hw0 + l15;
    const int half = ntq >> 1, odd = ntq & 1;
#pragma unroll
    for (int ct = 0; ct < 4; ++ct) {
      f32x4 acc = __builtin_amdgcn_mfma_f32_16x16x32_bf16(a2[ct * 2 + 0].v, b0, fz, 0, 0, 0);
      acc = __builtin_amdgcn_mfma_f32_16x16x32_bf16(a2[ct * 2 + 1].v, b1, acc, 0, 0, 0);
      const int cb = ct * 16 + lq * 4;
#pragma unroll
      for (int r = 0; r < 4; ++r) {
        const unsigned v = rc[(ct * 4 + r) * 2 + half];
        union { unsigned u; float f; } z;
        z.u = odd ? (v & 0xffff0000u) : (v << 16);
        __builtin_nontemporal_store(
            gamma * (acc[r] + bvr[ct][r]) + z.f,
            &op[(size_t)(cb + r) * HW_]);
      }
    }
  }
}

// ---------------------------------------------------------------------------
extern "C" void kernel_launch(void* const* d_in, const int* in_sizes, int n_in,
                              void* d_out, int out_size, void* d_ws, size_t ws_size,
                              hipStream_t stream) {
  const float* x   = (const float*)d_in[0];
  const float* wq  = (const float*)d_in[1];
  const float* bq  = (const float*)d_in[2];
  const float* wk  = (const float*)d_in[3];
  const float* bk  = (const float*)d_in[4];
  const float* wv  = (const float*)d_in[5];
  const float* bv  = (const float*)d_in[6];
  const float* gam = (const float*)d_in[7];
  float* out = (float*)d_out;

  short* wqkb  = (short*)d_ws;                        // 3072 bf16
  short* wvb   = wqkb + 3072;                         // 4096 bf16
  float* partE = (float*)(wvb + 4096 + 1024);         // pad to 16B; 4*576*256 f
  float* heat  = partE + (size_t)B_ * NCH_ * 256;     // 4*256 floats

  k_prep   <<<1, 256, 0, stream>>>(wq, wk, wv, wqkb, wvb);
  k_energy <<<dim3(NCH_, B_), 512, 0, stream>>>(x, wqkb, bq, bk, partE);
  k_softmax<<<dim3(B_),       256, 0, stream>>>(partE, heat);
  k_mix    <<<dim3(HW_ / 16, B_), 256, 0, stream>>>(x, heat, wvb, bv, gam, out);
}